// Round 1
// baseline (730.412 us; speedup 1.0000x reference)
//
#include <hip/hip_runtime.h>
#include <hip/hip_bf16.h>
#include <cstdint>

#define B_  4
#define L_  4096
#define D_  1024
#define H_  16
#define P_  5
#define Dh_ 64
#define FF_ 2048
#define M_  (B_*L_)    // 16384 tokens
#define HP_ (H_*P_)    // 80

typedef __bf16 bf16;
typedef __bf16 bf16x4 __attribute__((ext_vector_type(4)));
typedef __bf16 bf16x8 __attribute__((ext_vector_type(8)));
typedef float  f32x4  __attribute__((ext_vector_type(4)));
typedef int    i32x4  __attribute__((ext_vector_type(4)));
typedef unsigned int u32;

__device__ __forceinline__ void async16(const void* g, void* l) {
  __builtin_amdgcn_global_load_lds(
      (const __attribute__((address_space(1))) u32*)g,
      (__attribute__((address_space(3))) u32*)l, 16, 0, 0);
}

// ---------------- prep: split hidden to bf16 hi/lo, widen int8 weights to bf16 (exact) ----
__global__ __launch_bounds__(256) void prep_kernel(
    const float* __restrict__ hidden, const int* __restrict__ w1q,
    const int* __restrict__ w2q,
    bf16* __restrict__ Ahi, bf16* __restrict__ Alo,
    bf16* __restrict__ W1b, bf16* __restrict__ W2b,
    float* __restrict__ entSlot)
{
  const int tid = blockIdx.x * blockDim.x + threadIdx.x;
  const int nth = gridDim.x * blockDim.x;
  for (int i = tid; i < (M_*D_/4); i += nth) {
    f32x4 v = ((const f32x4*)hidden)[i];
    bf16x4 hi, lo;
#pragma unroll
    for (int j = 0; j < 4; ++j) {
      bf16 h = (bf16)v[j];
      hi[j] = h;
      lo[j] = (bf16)(v[j] - (float)h);
    }
    ((bf16x4*)Ahi)[i] = hi;
    ((bf16x4*)Alo)[i] = lo;
  }
  for (int i = tid; i < (FF_*D_/4); i += nth) {
    i32x4 w = ((const i32x4*)w1q)[i];
    bf16x4 b;
#pragma unroll
    for (int j = 0; j < 4; ++j) b[j] = (bf16)(float)w[j];
    ((bf16x4*)W1b)[i] = b;
  }
  for (int i = tid; i < (HP_*FF_/4); i += nth) {
    i32x4 w = ((const i32x4*)w2q)[i];
    bf16x4 b;
#pragma unroll
    for (int j = 0; j < 4; ++j) b[j] = (bf16)(float)w[j];
    ((bf16x4*)W2b)[i] = b;
  }
  if (tid == 0) *entSlot = 0.0f;
}

// ---------------- GEMM1: h = A @ W1^T (split hi/lo), scale s1, +b1, GELU(erf), split g ----
__global__ __launch_bounds__(256, 2) void gemm1_kernel(
    const bf16* __restrict__ Ahi, const bf16* __restrict__ Alo,
    const bf16* __restrict__ W1b, const float* __restrict__ s1,
    const float* __restrict__ b1,
    bf16* __restrict__ Ghi, bf16* __restrict__ Glo)
{
  __shared__ bf16 Ah[128*32];
  __shared__ bf16 Al[128*32];
  __shared__ bf16 Bw[128*32];
  const int t    = threadIdx.x;
  const int bn   = blockIdx.x & 15;   // FF blocks (16)
  const int bm   = blockIdx.x >> 4;   // token blocks (128)
  const int wid  = t >> 6;
  const int lane = t & 63;
  const int wm = wid >> 1, wn = wid & 1;
  const int l15 = lane & 15, l16 = lane >> 4;

  f32x4 acc[4][4] = {};

  for (int kt = 0; kt < 32; ++kt) {
    const int k0 = kt * 32;
    __syncthreads();
#pragma unroll
    for (int r = 0; r < 2; ++r) {
      const int f = r * 256 + t;
      const int row = f >> 2, c8 = (f & 3) << 3;
      const size_t ga = (size_t)(bm * 128 + row) * D_ + k0 + c8;
      async16(Ahi + ga, &Ah[f * 8]);
      async16(Alo + ga, &Al[f * 8]);
      const size_t gb = (size_t)(bn * 128 + row) * D_ + k0 + c8;
      async16(W1b + gb, &Bw[f * 8]);
    }
    __syncthreads();

    bf16x8 ah[4], al[4], bb[4];
    const int kk = l16 * 8;
#pragma unroll
    for (int i = 0; i < 4; ++i) {
      const int rowA = wm * 64 + i * 16 + l15;
      const int rowB = wn * 64 + i * 16 + l15;
      ah[i] = *(const bf16x8*)&Ah[rowA * 32 + kk];
      al[i] = *(const bf16x8*)&Al[rowA * 32 + kk];
      bb[i] = *(const bf16x8*)&Bw[rowB * 32 + kk];
    }
#pragma unroll
    for (int i = 0; i < 4; ++i)
#pragma unroll
      for (int j = 0; j < 4; ++j) {
        acc[i][j] = __builtin_amdgcn_mfma_f32_16x16x32_bf16(ah[i], bb[j], acc[i][j], 0, 0, 0);
        acc[i][j] = __builtin_amdgcn_mfma_f32_16x16x32_bf16(al[i], bb[j], acc[i][j], 0, 0, 0);
      }
  }

  // epilogue: dequant-scale, bias, exact GELU, split to bf16 hi/lo
#pragma unroll
  for (int i = 0; i < 4; ++i) {
    const int grow0 = bm * 128 + wm * 64 + i * 16 + (l16 << 2);
#pragma unroll
    for (int j = 0; j < 4; ++j) {
      const int gcol = bn * 128 + wn * 64 + j * 16 + l15;
      const float sc = s1[gcol];
      const float bi = b1[gcol];
#pragma unroll
      for (int r = 0; r < 4; ++r) {
        const float h = acc[i][j][r] * sc + bi;
        const float g = 0.5f * h * (1.0f + erff(h * 0.70710678118654752f));
        const bf16 gh = (bf16)g;
        const bf16 gl = (bf16)(g - (float)gh);
        const size_t o = (size_t)(grow0 + r) * FF_ + gcol;
        Ghi[o] = gh;
        Glo[o] = gl;
      }
    }
  }
}

// ---------------- GEMM2: logits = g @ W2^T (split hi/lo), scale s2, +b2 ----
__global__ __launch_bounds__(256, 2) void gemm2_kernel(
    const bf16* __restrict__ Ghi, const bf16* __restrict__ Glo,
    const bf16* __restrict__ W2b, const float* __restrict__ s2,
    const float* __restrict__ b2, float* __restrict__ logits)
{
  __shared__ bf16 Gh[128*32];
  __shared__ bf16 Gl[128*32];
  __shared__ bf16 Wt[80*32];
  const int t = threadIdx.x;
  const int bm = blockIdx.x;        // 128 token-blocks
  const int wid = t >> 6, lane = t & 63;
  const int l15 = lane & 15, l16 = lane >> 4;

  f32x4 acc[2][5] = {};

  for (int kt = 0; kt < 64; ++kt) {
    const int k0 = kt * 32;
    __syncthreads();
#pragma unroll
    for (int r = 0; r < 2; ++r) {
      const int f = r * 256 + t;
      const int row = f >> 2, c8 = (f & 3) << 3;
      const size_t ga = (size_t)(bm * 128 + row) * FF_ + k0 + c8;
      async16(Ghi + ga, &Gh[f * 8]);
      async16(Glo + ga, &Gl[f * 8]);
    }
    {
      const int f = t;  // chunks 0..255
      async16(W2b + (size_t)(f >> 2) * FF_ + k0 + ((f & 3) << 3), &Wt[f * 8]);
      if (t < 64) {
        const int f2 = 256 + t;  // chunks 256..319
        async16(W2b + (size_t)(f2 >> 2) * FF_ + k0 + ((f2 & 3) << 3), &Wt[f2 * 8]);
      }
    }
    __syncthreads();

    bf16x8 ah[2], al[2], bw[5];
    const int kk = l16 * 8;
#pragma unroll
    for (int i = 0; i < 2; ++i) {
      const int row = wid * 32 + i * 16 + l15;
      ah[i] = *(const bf16x8*)&Gh[row * 32 + kk];
      al[i] = *(const bf16x8*)&Gl[row * 32 + kk];
    }
#pragma unroll
    for (int j = 0; j < 5; ++j) {
      const int row = j * 16 + l15;
      bw[j] = *(const bf16x8*)&Wt[row * 32 + kk];
    }
#pragma unroll
    for (int i = 0; i < 2; ++i)
#pragma unroll
      for (int j = 0; j < 5; ++j) {
        acc[i][j] = __builtin_amdgcn_mfma_f32_16x16x32_bf16(ah[i], bw[j], acc[i][j], 0, 0, 0);
        acc[i][j] = __builtin_amdgcn_mfma_f32_16x16x32_bf16(al[i], bw[j], acc[i][j], 0, 0, 0);
      }
  }

#pragma unroll
  for (int i = 0; i < 2; ++i) {
    const int grow0 = bm * 128 + wid * 32 + i * 16 + (l16 << 2);
#pragma unroll
    for (int j = 0; j < 5; ++j) {
      const int n = j * 16 + l15;
      const float sc = s2[n];
      const float bi = b2[n];
#pragma unroll
      for (int r = 0; r < 4; ++r)
        logits[(size_t)(grow0 + r) * HP_ + n] = acc[i][j][r] * sc + bi;
    }
  }
}

// ---------------- epilogue: softmax, entropy, eps floor, path combine ----
__global__ __launch_bounds__(256) void epilogue_kernel(
    const float* __restrict__ logits,
    const float* __restrict__ p0, const float* __restrict__ p1,
    const float* __restrict__ p2, const float* __restrict__ p3,
    const float* __restrict__ p4,
    const float* __restrict__ glt, const float* __restrict__ gel,
    float* __restrict__ out, float* __restrict__ entAcc)
{
  const int tk = blockIdx.x;          // token
  const int t = threadIdx.x;          // 256 threads -> 1024 elems (float4 each)
  const int h = t >> 4;               // head for this thread's 4 elems

  // learned temperature
  const float lt = glt[h];
  const float sp = (lt > 20.f) ? lt : log1pf(expf(lt));
  const float temp = fmaxf(sp, 1e-4f);

  float z[5];
#pragma unroll
  for (int p = 0; p < 5; ++p)
    z[p] = logits[(size_t)tk * HP_ + h * 5 + p] / temp;

  float m = fmaxf(fmaxf(fmaxf(z[0], z[1]), fmaxf(z[2], z[3])), z[4]);
  float e[5], s = 0.f;
#pragma unroll
  for (int p = 0; p < 5; ++p) { e[p] = expf(z[p] - m); s += e[p]; }
  const float inv = 1.f / s;
  float pr[5], pmax = 0.f, ent = 0.f;
#pragma unroll
  for (int p = 0; p < 5; ++p) {
    pr[p] = e[p] * inv;
    pmax = fmaxf(pmax, pr[p]);
    ent -= pr[p] * logf(fmaxf(pr[p], 1e-9f));
  }

  // token-adaptive epsilon floor
  float epsv[5], esum = 0.f;
#pragma unroll
  for (int p = 0; p < 5; ++p) {
    const float sg = 1.f / (1.f + expf(-gel[h * 5 + p]));
    epsv[p] = 0.05f * (1.f - pmax) * sg;
    esum += epsv[p];
  }
  float q[5];
#pragma unroll
  for (int p = 0; p < 5; ++p)
    q[p] = fminf(fmaxf(pr[p] * (1.f - esum) + epsv[p], 1e-9f), 1.f);

  // weighted combine (vectorized, coalesced)
  const size_t i4 = (size_t)tk * 256 + t;
  const f32x4 a0 = ((const f32x4*)p0)[i4];
  const f32x4 a1 = ((const f32x4*)p1)[i4];
  const f32x4 a2 = ((const f32x4*)p2)[i4];
  const f32x4 a3 = ((const f32x4*)p3)[i4];
  const f32x4 a4 = ((const f32x4*)p4)[i4];
  f32x4 o;
#pragma unroll
  for (int j = 0; j < 4; ++j)
    o[j] = q[0]*a0[j] + q[1]*a1[j] + q[2]*a2[j] + q[3]*a3[j] + q[4]*a4[j];
  ((f32x4*)out)[i4] = o;

  // entropy block-reduce (one contributor per head)
  __shared__ float sh[16];
  if ((t & 15) == 0) sh[h] = ent;
  __syncthreads();
  if (t == 0) {
    float se = 0.f;
#pragma unroll
    for (int i = 0; i < 16; ++i) se += sh[i];
    atomicAdd(entAcc, se * (0.02f / (float)(M_ * H_)));
  }
}

extern "C" void kernel_launch(void* const* d_in, const int* in_sizes, int n_in,
                              void* d_out, int out_size, void* d_ws, size_t ws_size,
                              hipStream_t stream)
{
  const float* hidden = (const float*)d_in[0];
  const float* p0 = (const float*)d_in[1];
  const float* p1 = (const float*)d_in[2];
  const float* p2 = (const float*)d_in[3];
  const float* p3 = (const float*)d_in[4];
  const float* p4 = (const float*)d_in[5];
  const int*   w1q = (const int*)d_in[6];
  const float* s1 = (const float*)d_in[7];
  const float* b1 = (const float*)d_in[8];
  const int*   w2q = (const int*)d_in[9];
  const float* s2 = (const float*)d_in[10];
  const float* b2 = (const float*)d_in[11];
  const float* glt = (const float*)d_in[12];
  const float* gel = (const float*)d_in[13];
  float* out = (float*)d_out;

  char* ws = (char*)d_ws;
  bf16* Ahi = (bf16*)ws;  ws += (size_t)M_ * D_ * 2;    // 33.6 MB
  bf16* Alo = (bf16*)ws;  ws += (size_t)M_ * D_ * 2;    // 33.6 MB
  bf16* W1b = (bf16*)ws;  ws += (size_t)FF_ * D_ * 2;   // 4.2 MB
  bf16* W2b = (bf16*)ws;  ws += (size_t)HP_ * FF_ * 2;  // 0.33 MB
  bf16* Ghi = (bf16*)ws;  ws += (size_t)M_ * FF_ * 2;   // 67.1 MB
  bf16* Glo = (bf16*)ws;  ws += (size_t)M_ * FF_ * 2;   // 67.1 MB
  float* logits = (float*)ws;  ws += (size_t)M_ * HP_ * 4;  // 5.2 MB

  float* entSlot = out + (size_t)M_ * H_ * Dh_;  // out[4194304]

  prep_kernel<<<2048, 256, 0, stream>>>(hidden, w1q, w2q, Ahi, Alo, W1b, W2b, entSlot);
  gemm1_kernel<<<2048, 256, 0, stream>>>(Ahi, Alo, W1b, s1, b1, Ghi, Glo);
  gemm2_kernel<<<128, 256, 0, stream>>>(Ghi, Glo, W2b, s2, b2, logits);
  epilogue_kernel<<<16384, 256, 0, stream>>>(logits, p0, p1, p2, p3, p4, glt, gel, out, entSlot);
}